// Round 2
// baseline (1507.977 us; speedup 1.0000x reference)
//
#include <hip/hip_runtime.h>
#include <cstdint>
#include <cstddef>

// ---------------------------------------------------------------------------
// AttributeAttentionModule: out = softmax((sa@Wq^T+bq)(x@Wk^T+bk)^T/32) (x@Wv^T+bv)
// B=16384, D=3072, H=3, dh=1024.
// Stage 1: cast inputs fp32->bf16 into ws
// Stage 2: fused QKV GEMM — 256x256x64 tiles, 2-buffer LDS pipeline with
//          counted vmcnt(8) (never drains in main loop), raw s_barrier,
//          m201-style 4-phase schedule (16 MFMA per barrier pair), setprio,
//          zero-conflict XOR swizzle on 128B rows (round-0-verified layout).
// Stage 3: per-row tiny attention (1 wave/row)
// ---------------------------------------------------------------------------

typedef __bf16 bf16x8 __attribute__((ext_vector_type(8)));
typedef float f32x4 __attribute__((ext_vector_type(4)));

#define GLOBAL_AS __attribute__((address_space(1)))
#define LDS_AS __attribute__((address_space(3)))

__device__ __forceinline__ void async_load16(const __bf16* g, __bf16* l) {
    __builtin_amdgcn_global_load_lds((const GLOBAL_AS void*)g, (LDS_AS void*)l,
                                     16, 0, 0);
}

#define DIM 3072
#define BROWS 16384

// ---------------------------------------------------------------------------
// fp32 -> bf16 cast, 8 elements/thread (2x float4 load, 1x 16B store)
// ---------------------------------------------------------------------------
__global__ __launch_bounds__(256) void cast_f32_bf16(
    const float* __restrict__ src, __bf16* __restrict__ dst, int n8) {
    int i = blockIdx.x * 256 + threadIdx.x;
    if (i >= n8) return;
    const float4* s4 = reinterpret_cast<const float4*>(src);
    float4 a = s4[2 * i];
    float4 b = s4[2 * i + 1];
    bf16x8 o;
    o[0] = (__bf16)a.x; o[1] = (__bf16)a.y; o[2] = (__bf16)a.z; o[3] = (__bf16)a.w;
    o[4] = (__bf16)b.x; o[5] = (__bf16)b.y; o[6] = (__bf16)b.z; o[7] = (__bf16)b.w;
    *reinterpret_cast<bf16x8*>(dst + (size_t)i * 8) = o;
}

// ---------------------------------------------------------------------------
// Fused QKV GEMM: C = A @ W^T + bias. Grid: 2304 = 64 m-blocks x 36 n-blocks
// (n-block 0..11 Q, 12..23 K, 24..35 V). Block tile 256x256, K-step 64.
// 8 waves in 2x4; each wave 128x64 output (8x4 grid of 16x16x32 MFMAs,
// 64 MFMA per K-tile, two k-halves of 32).
//
// LDS: 2 buffers x (A 32KB + B 32KB) = 128KB. Tile layout [256][64] bf16,
// 128B rows of 8 x 16B chunks; global chunk c of row r stored at slot
// c ^ (r&7) (measured zero bank conflicts in round 0 at identical read
// pattern: 16 lanes sharing chunk, rows base+lr). Swizzle applied by
// permuting each lane's *global* source chunk; LDS dests stay linear
// (global_load_lds requirement).
//
// Pipeline: compute tile t from buf[t&1] while buf[t^1] receives t+1's
// in-flight loads. End of tile t: after all waves' reads of buf[t&1] have
// returned (lgkmcnt(0) + barrier), issue tile t+2's 8 loads into it, then
// s_waitcnt vmcnt(8) -> t+1's loads done, t+2's stay in flight across the
// barrier. vmcnt never drains to 0 in the main loop.
//
// Per-phase template (m201): {ds_reads; s_barrier; lgkmcnt(0); setprio(1);
// 16 MFMA; setprio(0); s_barrier} x 4 phases per K-tile.
// ---------------------------------------------------------------------------

#define BAR __builtin_amdgcn_s_barrier();
#define PRIO1 __builtin_amdgcn_s_setprio(1);
#define PRIO0 __builtin_amdgcn_s_setprio(0);
#define WAIT8 asm volatile("s_waitcnt vmcnt(8)" ::: "memory");
#define WAIT0 asm volatile("s_waitcnt vmcnt(0)" ::: "memory");
#define LGKM0 asm volatile("s_waitcnt lgkmcnt(0)" ::: "memory"); \
              __builtin_amdgcn_sched_barrier(0);

// fragment reads: af[q] = A rows wm*128 + H*64 + q*16 + lr, k-chunk lc+4*KH
#define LOADA(B_, KH, H) \
    _Pragma("unroll") \
    for (int q = 0; q < 4; ++q) \
        af[q] = *reinterpret_cast<const bf16x8*>( \
            &lds[B_][aof##KH + (H) * 4096 + q * 1024]);
#define LOADB(B_, KH) \
    _Pragma("unroll") \
    for (int q = 0; q < 4; ++q) \
        bfv[q] = *reinterpret_cast<const bf16x8*>( \
            &lds[B_][bof##KH + q * 1024]);

#define MFMAH(H_) \
    _Pragma("unroll") \
    for (int mt = 0; mt < 4; ++mt) \
    _Pragma("unroll") \
    for (int nt = 0; nt < 4; ++nt) \
        acc[(H_) * 4 + mt][nt] = __builtin_amdgcn_mfma_f32_16x16x32_bf16( \
            af[mt], bfv[nt], acc[(H_) * 4 + mt][nt], 0, 0, 0);

// stage one K-tile (A+B) into buffer B_ at k-elem offset OFF: 8 loads/thread
#define STAGE8(B_, OFF) \
    _Pragma("unroll") \
    for (int l = 0; l < 4; ++l) \
        async_load16(aptr[l] + (OFF), &lds[B_][(l * 512 + tid) * 8]); \
    _Pragma("unroll") \
    for (int l = 0; l < 4; ++l) \
        async_load16(wptr[l] + (OFF), &lds[B_][16384 + (l * 512 + tid) * 8]);

// full tile: 4 phases; stages t+2 into its own buffer during ph4.
#define TILE(B_) { \
    bf16x8 af[4], bfv[4]; \
    LOADB(B_, 0) LOADA(B_, 0, 0) \
    BAR LGKM0 \
    PRIO1 MFMAH(0) PRIO0 BAR \
    LOADA(B_, 0, 1) \
    BAR LGKM0 \
    PRIO1 MFMAH(1) PRIO0 BAR \
    LOADB(B_, 1) LOADA(B_, 1, 0) \
    BAR LGKM0 \
    PRIO1 MFMAH(0) PRIO0 BAR \
    LOADA(B_, 1, 1) \
    LGKM0 BAR \
    STAGE8(B_, kbase) \
    PRIO1 MFMAH(1) PRIO0 \
    WAIT8 BAR \
    kbase += 64; \
}

// second-to-last tile: no stage; drain remaining loads (vmcnt 0).
#define TILE_NS(B_) { \
    bf16x8 af[4], bfv[4]; \
    LOADB(B_, 0) LOADA(B_, 0, 0) \
    BAR LGKM0 \
    PRIO1 MFMAH(0) PRIO0 BAR \
    LOADA(B_, 0, 1) \
    BAR LGKM0 \
    PRIO1 MFMAH(1) PRIO0 BAR \
    LOADB(B_, 1) LOADA(B_, 1, 0) \
    BAR LGKM0 \
    PRIO1 MFMAH(0) PRIO0 BAR \
    LOADA(B_, 1, 1) \
    BAR LGKM0 \
    PRIO1 MFMAH(1) PRIO0 \
    WAIT0 BAR \
}

// last tile: pure reads + MFMA (compiler inserts waits), no barriers needed.
#define TILE_LAST(B_) { \
    bf16x8 af[4], bfv[4]; \
    LOADB(B_, 0) LOADA(B_, 0, 0) MFMAH(0) \
    LOADA(B_, 0, 1) MFMAH(1) \
    LOADB(B_, 1) LOADA(B_, 1, 0) MFMAH(0) \
    LOADA(B_, 1, 1) MFMAH(1) \
}

__global__ __launch_bounds__(512, 2) void gemm_qkv(
    const __bf16* __restrict__ xb, const __bf16* __restrict__ sb,
    const __bf16* __restrict__ wqb, const __bf16* __restrict__ wkb,
    const __bf16* __restrict__ wvb,
    const float* __restrict__ bq, const float* __restrict__ bk,
    const float* __restrict__ bv,
    __bf16* __restrict__ qo, __bf16* __restrict__ ko, __bf16* __restrict__ vo) {

    // per buffer: A tile elems [0,16384), B tile [16384,32768)
    __shared__ __bf16 lds[2][32768];

    const int tid  = threadIdx.x;
    const int lane = tid & 63;
    const int wave = tid >> 6;    // 0..7
    const int wm   = wave >> 2;   // 0..1  (m half: 128 rows)
    const int wn   = wave & 3;    // 0..3  (n quarter: 64 cols)

    // XCD-chunked swizzle: 2304 = 8 XCDs x 288; within a chunk bn varies
    // fastest so 36 consecutive blocks share one 1.5 MB A-panel in L2.
    const int bid  = blockIdx.x;
    const int swz  = (bid & 7) * 288 + (bid >> 3);
    const int bn   = swz % 36;
    const int bm   = swz / 36;
    const int proj = bn / 12;             // 0=Q 1=K 2=V
    const int n0   = (bn % 12) * 256;
    const int m0   = bm * 256;

    const __bf16* A = (proj == 0) ? sb : xb;
    const __bf16* W = (proj == 0) ? wqb : (proj == 1 ? wkb : wvb);
    const float*  bias = (proj == 0) ? bq : (proj == 1 ? bk : bv);
    __bf16* O = (proj == 0) ? qo : (proj == 1 ? ko : vo);

    // staging: per l in 0..3 thread owns 16B chunk idx = l*512+tid:
    // lds row = idx>>3 = l*64 + (tid>>3), stored slot = tid&7, fetched
    // global chunk = slot ^ (row&7) = (tid&7) ^ ((tid>>3)&7)  [l*64 = 0 mod 8].
    // Per wave: 8 rows x full 128B windows, perfectly coalesced.
    const int trow8 = tid >> 3;                       // 0..63
    const int gch   = (tid & 7) ^ (trow8 & 7);
    const __bf16* aptr[4];
    const __bf16* wptr[4];
#pragma unroll
    for (int l = 0; l < 4; ++l) {
        aptr[l] = A + (size_t)(m0 + l * 64 + trow8) * DIM + gch * 8;
        wptr[l] = W + (size_t)(n0 + l * 64 + trow8) * DIM + gch * 8;
    }

    // fragment-read offsets: row r = base + lr (base = wm*128 or wn*64,
    // both = 0 mod 16 -> r&7 = lr&7); logical chunk cch = lc + 4*kh;
    // slot = cch ^ (lr&7) -> per-lane constant per k-half.
    const int lr  = lane & 15;
    const int lc  = lane >> 4;
    const int s0  = lc ^ (lr & 7);
    const int aof0 = (wm * 128 + lr) * 64 + s0 * 8;
    const int aof1 = (wm * 128 + lr) * 64 + (s0 ^ 4) * 8;
    const int bof0 = 16384 + (wn * 64 + lr) * 64 + s0 * 8;
    const int bof1 = 16384 + (wn * 64 + lr) * 64 + (s0 ^ 4) * 8;

    f32x4 acc[8][4];
#pragma unroll
    for (int mt = 0; mt < 8; ++mt)
#pragma unroll
        for (int nt = 0; nt < 4; ++nt)
            acc[mt][nt] = (f32x4){0.f, 0.f, 0.f, 0.f};

    // prologue: stage tiles 0 and 1 (16 loads); wait oldest 8 (tile 0).
    STAGE8(0, 0)
    STAGE8(1, 64)
    WAIT8
    BAR

    int kbase = 128;   // k-elem offset of tile t+2 (first staged in loop: t=2)

    // main loop: 48 K-tiles; tiles 0..45 here (each stages t+2 <= 47).
    for (int tt = 0; tt < 23; ++tt) {
        TILE(0)
        TILE(1)
    }
    TILE_NS(0)     // tile 46: drains tile 47's loads (vmcnt 0)
    TILE_LAST(1)   // tile 47

    // epilogue: C/D layout col=lane&15, row=(lane>>4)*4+reg
    const int lrow4 = (lane >> 4) * 4;
#pragma unroll
    for (int nt = 0; nt < 4; ++nt) {
        const int n = n0 + wn * 64 + nt * 16 + lr;
        const float bn_f = bias[n];
#pragma unroll
        for (int mt = 0; mt < 8; ++mt) {
            const int mbase = m0 + wm * 128 + mt * 16 + lrow4;
#pragma unroll
            for (int r = 0; r < 4; ++r) {
                O[(size_t)(mbase + r) * DIM + n] =
                    (__bf16)(acc[mt][nt][r] + bn_f);
            }
        }
    }
}

// ---------------------------------------------------------------------------
// Tiny cross-attention: one wave per row. dh=1024 -> lane covers 8 d's per
// half (d = it*512 + lane*8). 9 scores via butterfly reduction.
// ---------------------------------------------------------------------------
__global__ __launch_bounds__(256) void attn_kernel(
    const __bf16* __restrict__ q, const __bf16* __restrict__ k,
    const __bf16* __restrict__ v, float* __restrict__ out) {
    const int wave = threadIdx.x >> 6;
    const int lane = threadIdx.x & 63;
    const size_t b = (size_t)blockIdx.x * 4 + wave;

    const __bf16* qr = q + b * DIM;
    const __bf16* kr = k + b * DIM;
    const __bf16* vr = v + b * DIM;

    float s[3][3] = {{0.f, 0.f, 0.f}, {0.f, 0.f, 0.f}, {0.f, 0.f, 0.f}};

#pragma unroll
    for (int it = 0; it < 2; ++it) {
        const int d0 = it * 512 + lane * 8;
        bf16x8 q8[3], k8[3];
#pragma unroll
        for (int h = 0; h < 3; ++h)
            q8[h] = *reinterpret_cast<const bf16x8*>(qr + h * 1024 + d0);
#pragma unroll
        for (int g = 0; g < 3; ++g)
            k8[g] = *reinterpret_cast<const bf16x8*>(kr + g * 1024 + d0);
#pragma unroll
        for (int h = 0; h < 3; ++h)
#pragma unroll
            for (int g = 0; g < 3; ++g) {
                float acc = 0.f;
#pragma unroll
                for (int j = 0; j < 8; ++j)
                    acc += (float)q8[h][j] * (float)k8[g][j];
                s[h][g] += acc;
            }
    }

    // wave butterfly reduce each of the 9 partial dots
#pragma unroll
    for (int h = 0; h < 3; ++h)
#pragma unroll
        for (int g = 0; g < 3; ++g) {
            float val = s[h][g];
#pragma unroll
            for (int off = 32; off > 0; off >>= 1)
                val += __shfl_xor(val, off, 64);
            s[h][g] = val;
        }

    // softmax over g (scale = 1/sqrt(1024) = 1/32)
    float w[3][3];
    const float scale = 0.03125f;
#pragma unroll
    for (int h = 0; h < 3; ++h) {
        float s0 = s[h][0] * scale, s1 = s[h][1] * scale, s2 = s[h][2] * scale;
        float mx = fmaxf(s0, fmaxf(s1, s2));
        float e0 = __expf(s0 - mx), e1 = __expf(s1 - mx), e2 = __expf(s2 - mx);
        float inv = 1.f / (e0 + e1 + e2);
        w[h][0] = e0 * inv; w[h][1] = e1 * inv; w[h][2] = e2 * inv;
    }

    // out[h,d] = sum_g w[h][g] * V[g,d]
#pragma unroll
    for (int it = 0; it < 2; ++it) {
        const int d0 = it * 512 + lane * 8;
        bf16x8 v8[3];
#pragma unroll
        for (int g = 0; g < 3; ++g)
            v8[g] = *reinterpret_cast<const bf16x8*>(vr + g * 1024 + d0);
#pragma unroll
        for (int h = 0; h < 3; ++h) {
            float o[8];
#pragma unroll
            for (int j = 0; j < 8; ++j)
                o[j] = w[h][0] * (float)v8[0][j] + w[h][1] * (float)v8[1][j] +
                       w[h][2] * (float)v8[2][j];
            float* op = out + b * DIM + h * 1024 + d0;
            float4 lo = {o[0], o[1], o[2], o[3]};
            float4 hi = {o[4], o[5], o[6], o[7]};
            *reinterpret_cast<float4*>(op) = lo;
            *reinterpret_cast<float4*>(op + 4) = hi;
        }
    }
}

// ---------------------------------------------------------------------------
extern "C" void kernel_launch(void* const* d_in, const int* in_sizes, int n_in,
                              void* d_out, int out_size, void* d_ws,
                              size_t ws_size, hipStream_t stream) {
    const float* x  = (const float*)d_in[0];
    const float* sa = (const float*)d_in[1];
    const float* Wq = (const float*)d_in[2];
    const float* bq = (const float*)d_in[3];
    const float* Wk = (const float*)d_in[4];
    const float* bk = (const float*)d_in[5];
    const float* Wv = (const float*)d_in[6];
    const float* bv = (const float*)d_in[7];
    float* out = (float*)d_out;

    const size_t B = BROWS, D = DIM;
    __bf16* ws  = (__bf16*)d_ws;
    __bf16* xb  = ws;              // B*D
    __bf16* sb  = xb + B * D;      // B*D
    __bf16* wqb = sb + B * D;      // D*D
    __bf16* wkb = wqb + D * D;
    __bf16* wvb = wkb + D * D;
    __bf16* qo  = wvb + D * D;     // B*D
    __bf16* ko  = qo + B * D;
    __bf16* vo  = ko + B * D;
    // total: 5*B*D + 3*D*D bf16 = ~534 MB

    const int nBD8 = (int)(B * D / 8);   // 6291456
    const int nDD8 = (int)(D * D / 8);   // 1179648

    cast_f32_bf16<<<nBD8 / 256, 256, 0, stream>>>(x, xb, nBD8);
    cast_f32_bf16<<<nBD8 / 256, 256, 0, stream>>>(sa, sb, nBD8);
    cast_f32_bf16<<<nDD8 / 256, 256, 0, stream>>>(Wq, wqb, nDD8);
    cast_f32_bf16<<<nDD8 / 256, 256, 0, stream>>>(Wk, wkb, nDD8);
    cast_f32_bf16<<<nDD8 / 256, 256, 0, stream>>>(Wv, wvb, nDD8);

    gemm_qkv<<<2304, 512, 0, stream>>>(xb, sb, wqb, wkb, wvb, bq, bk, bv,
                                       qo, ko, vo);

    attn_kernel<<<BROWS / 4, 256, 0, stream>>>(qo, ko, vo, out);
}

// Round 3
// 1418.051 us; speedup vs baseline: 1.0634x; 1.0634x over previous
//
#include <hip/hip_runtime.h>
#include <cstdint>
#include <cstddef>

// ---------------------------------------------------------------------------
// AttributeAttentionModule: out = softmax((sa@Wq^T+bq)(x@Wk^T+bk)^T/32) (x@Wv^T+bv)
// B=16384, D=3072, H=3, dh=1024.
// Stage 1: cast inputs fp32->bf16 into ws
// Stage 2: fused QKV GEMM — 256x256x32 tiles, 4-deep LDS pipeline (R1
//          structure: 2 barriers/tile, counted vmcnt(4), compiler-scheduled
//          lgkmcnt), paired-row conflict-free LDS layout (128B lines),
//          cross-phase register fragment prefetch to overlap LDS with MFMA.
// Stage 3: per-row tiny attention (1 wave/row)
// ---------------------------------------------------------------------------

typedef __bf16 bf16x8 __attribute__((ext_vector_type(8)));
typedef float f32x4 __attribute__((ext_vector_type(4)));

#define GLOBAL_AS __attribute__((address_space(1)))
#define LDS_AS __attribute__((address_space(3)))

__device__ __forceinline__ void async_load16(const __bf16* g, __bf16* l) {
    __builtin_amdgcn_global_load_lds((const GLOBAL_AS void*)g, (LDS_AS void*)l,
                                     16, 0, 0);
}

#define DIM 3072
#define BROWS 16384

// ---------------------------------------------------------------------------
// fp32 -> bf16 cast, 8 elements/thread (2x float4 load, 1x 16B store)
// ---------------------------------------------------------------------------
__global__ __launch_bounds__(256) void cast_f32_bf16(
    const float* __restrict__ src, __bf16* __restrict__ dst, int n8) {
    int i = blockIdx.x * 256 + threadIdx.x;
    if (i >= n8) return;
    const float4* s4 = reinterpret_cast<const float4*>(src);
    float4 a = s4[2 * i];
    float4 b = s4[2 * i + 1];
    bf16x8 o;
    o[0] = (__bf16)a.x; o[1] = (__bf16)a.y; o[2] = (__bf16)a.z; o[3] = (__bf16)a.w;
    o[4] = (__bf16)b.x; o[5] = (__bf16)b.y; o[6] = (__bf16)b.z; o[7] = (__bf16)b.w;
    *reinterpret_cast<bf16x8*>(dst + (size_t)i * 8) = o;
}

// ---------------------------------------------------------------------------
// Fused QKV GEMM: C = A @ W^T + bias. Grid: 2304 = 64 m x 36 n blocks
// (n-block 0..11 Q, 12..23 K, 24..35 V). Block 256x256, K-step 32.
// 8 waves 2x4; per-wave 128x64 = 8x4 grid of 16x16x32 MFMAs (32/K-tile).
//
// LDS: 4 buffers x (A 16KB + B 16KB) = 128KB. Paired-row layout: logical
// (row r in [0,256), 16B-chunk c in [0,4)) lives on 128B line L = r>>1 at
// slot s = (c + 4*(r&1)) ^ (L&7). Fragment reads (16 lanes: rows base+lr,
// chunk lc) then hit each of the 8 slot positions exactly twice (2-way =
// free; same distribution R2 measured at zero conflicts). Staging keeps
// LDS dests linear (global_load_lds rule); the swizzle is applied by
// permuting each thread's *global* source (row, chunk) — coalescing is
// unchanged vs R1 (16 x 64B windows per wave).
//
// Pipeline (R1 structure): compute tile t from buf[t&3] while staging
// t+3 into buf[(t+3)&3]; tile end = s_waitcnt vmcnt(4) + s_barrier ONLY.
// vmcnt(4) leaves tile t+3's 4 loads in flight and guarantees tiles
// <= t+2 complete — one tile EARLIER than needed for compute, which
// legalizes prefetching tile t+1's fragments during tile t's phase 2.
// Register fragment double-buffer: each MFMA cluster consumes frags
// loaded in the PREVIOUS phase, so ds_reads overlap MFMA instead of
// serializing with it (the R1/R2 ~50% MfmaUtil ceiling).
// ---------------------------------------------------------------------------

#define BAR __builtin_amdgcn_s_barrier();
#define PRIO1 __builtin_amdgcn_s_setprio(1);
#define PRIO0 __builtin_amdgcn_s_setprio(0);
#define WAIT4 asm volatile("s_waitcnt vmcnt(4)" ::: "memory");
#define WAIT0 asm volatile("s_waitcnt vmcnt(0)" ::: "memory");

// fragment loads: A frag (H*4+q) covers rows wm*128+(H*4+q)*16+lr, k 0..31
#define LDA(B_, DST, H) \
    _Pragma("unroll") \
    for (int q = 0; q < 4; ++q) \
        DST[q] = *reinterpret_cast<const bf16x8*>( \
            &lds[B_][aofs + ((H) * 4 + q) * 512]);
#define LDB(B_, DST) \
    _Pragma("unroll") \
    for (int q = 0; q < 4; ++q) \
        DST[q] = *reinterpret_cast<const bf16x8*>( \
            &lds[B_][bofs + q * 512]);

#define MFMA16(AF, BF, H) \
    _Pragma("unroll") \
    for (int mt = 0; mt < 4; ++mt) \
    _Pragma("unroll") \
    for (int nt = 0; nt < 4; ++nt) \
        acc[(H) * 4 + mt][nt] = __builtin_amdgcn_mfma_f32_16x16x32_bf16( \
            AF[mt], BF[nt], acc[(H) * 4 + mt][nt], 0, 0, 0);

// stage tile (k-elem offset KB_) into buffer SB_: 4 loads/thread (2 A + 2 W)
#define STAGE_A(SB_, KB_) \
    async_load16(aptr0 + (KB_), &lds[SB_][tid8]); \
    async_load16(aptr1 + (KB_), &lds[SB_][4096 + tid8]);
#define STAGE_W(SB_, KB_) \
    async_load16(wptr0 + (KB_), &lds[SB_][8192 + tid8]); \
    async_load16(wptr1 + (KB_), &lds[SB_][12288 + tid8]);

// Full tile: compute buffer B_, prefetch next tile's frags from NB_,
// stage into SB_ at k-offset kb. Entering: A0 = half0 frags of B_,
// B0C = B frags of B_. Exiting: A0 = half0 of NB_, B1N = B of NB_.
#define TILE(B_, NB_, SB_, A0, B0C, A1, B1N, WMACRO) { \
    LDA(B_, A1, 1) \
    STAGE_A(SB_, kb) \
    PRIO1 MFMA16(A0, B0C, 0) PRIO0 \
    LDA(NB_, A0, 0) \
    LDB(NB_, B1N) \
    STAGE_W(SB_, kb) \
    PRIO1 MFMA16(A1, B0C, 1) PRIO0 \
    WMACRO BAR \
    kb += 32; \
}

// No-stage tile (tail), optional wait/barrier via WMACRO.
#define TILE_NS(B_, NB_, A0, B0C, A1, B1N, WMACRO) { \
    LDA(B_, A1, 1) \
    PRIO1 MFMA16(A0, B0C, 0) PRIO0 \
    LDA(NB_, A0, 0) \
    LDB(NB_, B1N) \
    PRIO1 MFMA16(A1, B0C, 1) PRIO0 \
    WMACRO \
}

// Last tile: no prefetch.
#define TILE_LAST(B_, A0, B0C, A1) { \
    LDA(B_, A1, 1) \
    MFMA16(A0, B0C, 0) \
    MFMA16(A1, B0C, 1) \
}

__global__ __launch_bounds__(512, 2) void gemm_qkv(
    const __bf16* __restrict__ xb, const __bf16* __restrict__ sb,
    const __bf16* __restrict__ wqb, const __bf16* __restrict__ wkb,
    const __bf16* __restrict__ wvb,
    const float* __restrict__ bq, const float* __restrict__ bk,
    const float* __restrict__ bv,
    __bf16* __restrict__ qo, __bf16* __restrict__ ko, __bf16* __restrict__ vo) {

    // per buffer: A tile elems [0,8192), B tile [8192,16384); 4 buffers
    __shared__ __bf16 lds[4][16384];

    const int tid  = threadIdx.x;
    const int lane = tid & 63;
    const int wave = tid >> 6;    // 0..7
    const int wm   = wave >> 2;   // 0..1  (m half: 128 rows)
    const int wn   = wave & 3;    // 0..3  (n quarter: 64 cols)

    // XCD-chunked swizzle: 2304 = 8 XCDs x 288; within a chunk bn varies
    // fastest so 36 consecutive blocks share one 1.5 MB A-panel in L2.
    const int bid  = blockIdx.x;
    const int swz  = (bid & 7) * 288 + (bid >> 3);
    const int bn   = swz % 36;
    const int bm   = swz / 36;
    const int proj = bn / 12;             // 0=Q 1=K 2=V
    const int n0   = (bn % 12) * 256;
    const int m0   = bm * 256;

    const __bf16* A = (proj == 0) ? sb : xb;
    const __bf16* W = (proj == 0) ? wqb : (proj == 1 ? wkb : wvb);
    const float*  bias = (proj == 0) ? bq : (proj == 1 ? bk : bv);
    __bf16* O = (proj == 0) ? qo : (proj == 1 ? ko : vo);

    // staging: thread owns LDS chunk k = l*512 + tid (l=0,1), byte 16k.
    // Inverse of the paired-row layout: L = k>>3, slot s = k&7,
    // logical p = s ^ (L&7), row = 2L + (p>>2), chunk c = p&3.
    // With L&7 = (tid>>3)&7 (l*64 = 0 mod 8):
    const int p    = (tid & 7) ^ ((tid >> 3) & 7);
    const int ro   = 2 * (tid >> 3) + (p >> 2);     // row for l=0; +128 for l=1
    const int co   = (p & 3) * 8;                   // k-elem offset in row
    const __bf16* aptr0 = A + (size_t)(m0 + ro) * DIM + co;
    const __bf16* aptr1 = aptr0 + (size_t)128 * DIM;
    const __bf16* wptr0 = W + (size_t)(n0 + ro) * DIM + co;
    const __bf16* wptr1 = wptr0 + (size_t)128 * DIM;
    const int tid8 = tid * 8;

    // fragment-read offsets: lane (lr, lc) reads row base+f*16+lr chunk lc:
    // L = base/2 + f*8 + (lr>>1); L&7 = (lr>>1)&7;
    // slot sA = (lc + 4*(lr&1)) ^ ((lr>>1)&7)  — per-lane constant.
    // elem addr = (base/2 + f*8 + (lr>>1))*64 + sA*8 = ofs + f*512.
    const int lr  = lane & 15;
    const int lc  = lane >> 4;
    const int sA  = (lc + 4 * (lr & 1)) ^ ((lr >> 1) & 7);
    const int aofs = wm * 4096 + (lr >> 1) * 64 + sA * 8;
    const int bofs = 8192 + wn * 2048 + (lr >> 1) * 64 + sA * 8;

    f32x4 acc[8][4];
#pragma unroll
    for (int mt = 0; mt < 8; ++mt)
#pragma unroll
        for (int nt = 0; nt < 4; ++nt)
            acc[mt][nt] = (f32x4){0.f, 0.f, 0.f, 0.f};

    // prologue: stage tiles 0,1,2 (12 loads); vmcnt(4) -> tiles 0,1 done.
    STAGE_A(0, 0)  STAGE_W(0, 0)
    STAGE_A(1, 32) STAGE_W(1, 32)
    STAGE_A(2, 64) STAGE_W(2, 64)
    WAIT4
    BAR

    // fragment register double-buffer
    bf16x8 A0[4], A1[4], B0[4], B1[4];
    LDA(0, A0, 0)
    LDB(0, B0)

    int kb = 96;   // k-elem offset of next staged tile (tile 3)

    // main loop: tiles 0..91 (23 x 4); tile t stages t+3 (<= 94).
    for (int tt = 0; tt < 23; ++tt) {
        TILE(0, 1, 3, A0, B0, A1, B1, WAIT4)
        TILE(1, 2, 0, A0, B1, A1, B0, WAIT4)
        TILE(2, 3, 1, A0, B0, A1, B1, WAIT4)
        TILE(3, 0, 2, A0, B1, A1, B0, WAIT4)
    }
    // tail: t=92 stages tile 95 (kb=3040); then drain.
    TILE(0, 1, 3, A0, B0, A1, B1, WAIT4)
    TILE_NS(1, 2, A0, B1, A1, B0, WAIT0 BAR)   // tile 95 data valid after this
    TILE_NS(2, 3, A0, B0, A1, B1, )            // prefetches buf3 (tile 95)
    TILE_LAST(3, A0, B1, A1)

    // epilogue: C/D layout col=lane&15, row=(lane>>4)*4+reg
    const int lrow4 = (lane >> 4) * 4;
#pragma unroll
    for (int nt = 0; nt < 4; ++nt) {
        const int n = n0 + wn * 64 + nt * 16 + lr;
        const float bn_f = bias[n];
#pragma unroll
        for (int mt = 0; mt < 8; ++mt) {
            const int mbase = m0 + wm * 128 + mt * 16 + lrow4;
#pragma unroll
            for (int r = 0; r < 4; ++r) {
                O[(size_t)(mbase + r) * DIM + n] =
                    (__bf16)(acc[mt][nt][r] + bn_f);
            }
        }
    }
}

// ---------------------------------------------------------------------------
// Tiny cross-attention: one wave per row. dh=1024 -> lane covers 8 d's per
// half (d = it*512 + lane*8). 9 scores via butterfly reduction.
// ---------------------------------------------------------------------------
__global__ __launch_bounds__(256) void attn_kernel(
    const __bf16* __restrict__ q, const __bf16* __restrict__ k,
    const __bf16* __restrict__ v, float* __restrict__ out) {
    const int wave = threadIdx.x >> 6;
    const int lane = threadIdx.x & 63;
    const size_t b = (size_t)blockIdx.x * 4 + wave;

    const __bf16* qr = q + b * DIM;
    const __bf16* kr = k + b * DIM;
    const __bf16* vr = v + b * DIM;

    float s[3][3] = {{0.f, 0.f, 0.f}, {0.f, 0.f, 0.f}, {0.f, 0.f, 0.f}};

#pragma unroll
    for (int it = 0; it < 2; ++it) {
        const int d0 = it * 512 + lane * 8;
        bf16x8 q8[3], k8[3];
#pragma unroll
        for (int h = 0; h < 3; ++h)
            q8[h] = *reinterpret_cast<const bf16x8*>(qr + h * 1024 + d0);
#pragma unroll
        for (int g = 0; g < 3; ++g)
            k8[g] = *reinterpret_cast<const bf16x8*>(kr + g * 1024 + d0);
#pragma unroll
        for (int h = 0; h < 3; ++h)
#pragma unroll
            for (int g = 0; g < 3; ++g) {
                float acc = 0.f;
#pragma unroll
                for (int j = 0; j < 8; ++j)
                    acc += (float)q8[h][j] * (float)k8[g][j];
                s[h][g] += acc;
            }
    }

    // wave butterfly reduce each of the 9 partial dots
#pragma unroll
    for (int h = 0; h < 3; ++h)
#pragma unroll
        for (int g = 0; g < 3; ++g) {
            float val = s[h][g];
#pragma unroll
            for (int off = 32; off > 0; off >>= 1)
                val += __shfl_xor(val, off, 64);
            s[h][g] = val;
        }

    // softmax over g (scale = 1/sqrt(1024) = 1/32)
    float w[3][3];
    const float scale = 0.03125f;
#pragma unroll
    for (int h = 0; h < 3; ++h) {
        float s0 = s[h][0] * scale, s1 = s[h][1] * scale, s2 = s[h][2] * scale;
        float mx = fmaxf(s0, fmaxf(s1, s2));
        float e0 = __expf(s0 - mx), e1 = __expf(s1 - mx), e2 = __expf(s2 - mx);
        float inv = 1.f / (e0 + e1 + e2);
        w[h][0] = e0 * inv; w[h][1] = e1 * inv; w[h][2] = e2 * inv;
    }

    // out[h,d] = sum_g w[h][g] * V[g,d]
#pragma unroll
    for (int it = 0; it < 2; ++it) {
        const int d0 = it * 512 + lane * 8;
        bf16x8 v8[3];
#pragma unroll
        for (int g = 0; g < 3; ++g)
            v8[g] = *reinterpret_cast<const bf16x8*>(vr + g * 1024 + d0);
#pragma unroll
        for (int h = 0; h < 3; ++h) {
            float o[8];
#pragma unroll
            for (int j = 0; j < 8; ++j)
                o[j] = w[h][0] * (float)v8[0][j] + w[h][1] * (float)v8[1][j] +
                       w[h][2] * (float)v8[2][j];
            float* op = out + b * DIM + h * 1024 + d0;
            float4 lo = {o[0], o[1], o[2], o[3]};
            float4 hi = {o[4], o[5], o[6], o[7]};
            *reinterpret_cast<float4*>(op) = lo;
            *reinterpret_cast<float4*>(op + 4) = hi;
        }
    }
}

// ---------------------------------------------------------------------------
extern "C" void kernel_launch(void* const* d_in, const int* in_sizes, int n_in,
                              void* d_out, int out_size, void* d_ws,
                              size_t ws_size, hipStream_t stream) {
    const float* x  = (const float*)d_in[0];
    const float* sa = (const float*)d_in[1];
    const float* Wq = (const float*)d_in[2];
    const float* bq = (const float*)d_in[3];
    const float* Wk = (const float*)d_in[4];
    const float* bk = (const float*)d_in[5];
    const float* Wv = (const float*)d_in[6];
    const float* bv = (const float*)d_in[7];
    float* out = (float*)d_out;

    const size_t B = BROWS, D = DIM;
    __bf16* ws  = (__bf16*)d_ws;
    __bf16* xb  = ws;              // B*D
    __bf16* sb  = xb + B * D;      // B*D
    __bf16* wqb = sb + B * D;      // D*D
    __bf16* wkb = wqb + D * D;
    __bf16* wvb = wkb + D * D;
    __bf16* qo  = wvb + D * D;     // B*D
    __bf16* ko  = qo + B * D;
    __bf16* vo  = ko + B * D;
    // total: 5*B*D + 3*D*D bf16 = ~534 MB

    const int nBD8 = (int)(B * D / 8);   // 6291456
    const int nDD8 = (int)(D * D / 8);   // 1179648

    cast_f32_bf16<<<nBD8 / 256, 256, 0, stream>>>(x, xb, nBD8);
    cast_f32_bf16<<<nBD8 / 256, 256, 0, stream>>>(sa, sb, nBD8);
    cast_f32_bf16<<<nDD8 / 256, 256, 0, stream>>>(Wq, wqb, nDD8);
    cast_f32_bf16<<<nDD8 / 256, 256, 0, stream>>>(Wk, wkb, nDD8);
    cast_f32_bf16<<<nDD8 / 256, 256, 0, stream>>>(Wv, wvb, nDD8);

    gemm_qkv<<<2304, 512, 0, stream>>>(xb, sb, wqb, wkb, wvb, bq, bk, bv,
                                       qo, ko, vo);

    attn_kernel<<<BROWS / 4, 256, 0, stream>>>(qo, ko, vo, out);
}